// Round 9
// baseline (18989.638 us; speedup 1.0000x reference)
//
#include <hip/hip_runtime.h>

// LSTM-CRF on MI355X.
// Pipeline: embed -> wpack -> gemm(gin L0) -> lstm L0 -> wpack -> gemm L1 -> lstm L1
//           -> feats -> viterbi.
// Recurrence: 32 WGs x 1024 thr; each WG owns 16 units for BOTH directions and
// interleaves them: while dir0's h(t+1) propagates through the LLC (~1,600cy), the WG
// computes dir1's step. dir1's poll is pre-issued at loop top (h is a full loop old ->
// single-load hit, hidden under dir0's spin/finish). Round-8 lesson: keep s_barrier
// (hardware sync ~100cy beats LDS flag hops). Fast gates via v_exp_f32 + v_rcp_f32
// (score threshold 227; libm expf/tanhf branches cost ~300cy/step on the serial path).

#define T_SEQ 4096
#define HPAD  512
#define NTAG  16

// ---------------- workspace layout (bytes) ----------------
// x0   : [4096][512]  f32   8388608  @ 0
// x1   : [4096][1024] f32  16777216  @ 8388608
// x2   : [4096][1024] f32  16777216  @ 25165824   (doubles as Wp scratch pre-lstm-L1)
// gin  : [2][4096][2048] f32 67108864 @ 41943040
// feats: [4096][16] f32     262144  @ 109051904
// bptr : [4096][16] i32     262144  @ 109314048   (first 16KB doubles as bp pre-viterbi)
// hcomm: [2][2][512] u64     16384  @ 109576192

__global__ void zero_k(float* __restrict__ p, int n) {
  int i = blockIdx.x * blockDim.x + threadIdx.x;
  int stride = gridDim.x * blockDim.x;
  for (; i < n; i += stride) p[i] = 0.0f;
}

__global__ void embed_k(const int* __restrict__ sent, const float* __restrict__ ew,
                        float* __restrict__ x0) {
  int t = blockIdx.x;
  int row = sent[t];
  for (int k = threadIdx.x; k < HPAD; k += blockDim.x)
    x0[(size_t)t * HPAD + k] = (k < 500) ? ew[(size_t)row * 500 + k] : 0.0f;
}

// Pre-pack W into dense padded layout Wp[dir][2048][KAp] (+ fused bias bp[dir][2048]).
__global__ __launch_bounds__(256) void wpack_k(
    const float* __restrict__ wih, const float* __restrict__ bih,
    const float* __restrict__ bhh, int Kreal, int KAp,
    float* __restrict__ Wp, float* __restrict__ bp) {
  const int n = blockIdx.x;              // 0..2047
  const int dir = blockIdx.y;
  const int gate = n >> 9, j = n & 511;
  const int row = gate * 500 + j;
  const float* W = wih + (size_t)dir * 2000 * Kreal;
  float* dst = Wp + ((size_t)dir * 2048 + n) * KAp;
  for (int k = threadIdx.x; k < KAp; k += 256) {
    int half = k >> 9, jk = k & 511;
    float v = 0.0f;
    if (j < 500 && jk < 500)
      v = W[(size_t)row * Kreal + half * 500 + jk];
    dst[k] = v;
  }
  if (threadIdx.x == 0)
    bp[dir * 2048 + n] = (j < 500) ? bih[dir * 2000 + row] + bhh[dir * 2000 + row] : 0.0f;
}

// G[dir][t][n] = sum_k A[t][k] * Wp[dir][n][k] + bp[dir][n]  (dense, no branches)
__global__ __launch_bounds__(256) void gin_gemm_k(
    const float* __restrict__ A, int KA,
    const float* __restrict__ Wp, const float* __restrict__ bp,
    float* __restrict__ G) {
  const int dir = blockIdx.z;
  const int bm = blockIdx.y, bn = blockIdx.x;
  const float* W = Wp + (size_t)dir * 2048 * KA;

  __shared__ float As[16][128];
  __shared__ float Bs[16][128];

  const int tid = threadIdx.x;
  const int tx = tid & 15, ty = tid >> 4;
  float acc[8][8] = {};

  for (int k0 = 0; k0 < KA; k0 += 16) {
#pragma unroll
    for (int q = 0; q < 2; q++) {
      int f4 = tid + q * 256;              // 0..511
      int m = f4 >> 2, kc = (f4 & 3) * 4;
      float4 av = *reinterpret_cast<const float4*>(A + (size_t)(bm * 128 + m) * KA + k0 + kc);
      As[kc + 0][m] = av.x; As[kc + 1][m] = av.y;
      As[kc + 2][m] = av.z; As[kc + 3][m] = av.w;
    }
#pragma unroll
    for (int q = 0; q < 2; q++) {
      int f4 = tid + q * 256;
      int n = f4 >> 2, kc = (f4 & 3) * 4;
      float4 bv = *reinterpret_cast<const float4*>(W + (size_t)(bn * 128 + n) * KA + k0 + kc);
      Bs[kc + 0][n] = bv.x; Bs[kc + 1][n] = bv.y;
      Bs[kc + 2][n] = bv.z; Bs[kc + 3][n] = bv.w;
    }
    __syncthreads();
#pragma unroll
    for (int kk = 0; kk < 16; kk++) {
      float a[8], b[8];
      *reinterpret_cast<float4*>(&a[0]) = *reinterpret_cast<const float4*>(&As[kk][ty * 8]);
      *reinterpret_cast<float4*>(&a[4]) = *reinterpret_cast<const float4*>(&As[kk][ty * 8 + 4]);
      *reinterpret_cast<float4*>(&b[0]) = *reinterpret_cast<const float4*>(&Bs[kk][tx * 8]);
      *reinterpret_cast<float4*>(&b[4]) = *reinterpret_cast<const float4*>(&Bs[kk][tx * 8 + 4]);
#pragma unroll
      for (int i = 0; i < 8; i++)
#pragma unroll
        for (int j = 0; j < 8; j++) acc[i][j] = fmaf(a[i], b[j], acc[i][j]);
    }
    __syncthreads();
  }
#pragma unroll
  for (int i = 0; i < 8; i++) {
#pragma unroll
    for (int j = 0; j < 8; j++) {
      int m = bm * 128 + ty * 8 + i;
      int nn = bn * 128 + tx * 8 + j;
      G[((size_t)dir * T_SEQ + m) * 2048 + nn] = acc[i][j] + bp[dir * 2048 + nn];
    }
  }
}

__device__ __forceinline__ unsigned long long pack_hv(unsigned tag, float h) {
  return (unsigned long long)tag | ((unsigned long long)__float_as_uint(h) << 32);
}

// fast sigmoid/tanh: v_exp_f32 + v_rcp_f32, branch-free, correct saturation.
__device__ __forceinline__ float fsig(float x) {
  float e = __expf(-x);
  return __builtin_amdgcn_rcpf(1.0f + e);
}
__device__ __forceinline__ float ftanhf(float x) {
  return fmaf(2.0f, fsig(x + x), -1.0f);
}

__global__ void hinit_k(const float* __restrict__ h0, int layer,
                        unsigned long long* __restrict__ hcomm) {
  int i = blockIdx.x * blockDim.x + threadIdx.x;   // 0..2047
  int dir = i >> 10, par = (i >> 9) & 1, j = i & 511;
  unsigned long long v;
  if (par == 0) {
    float h = (j < 500) ? h0[(layer * 2 + dir) * 500 + j] : 0.0f;
    v = pack_hv(0u, h);
  } else {
    v = 0xFFFFFFFFull;   // sentinel tag, value 0
  }
  hcomm[(size_t)(dir * 2 + par) * HPAD + j] = v;
}

// Persistent recurrence kernel: 32 WGs x 1024 threads; WG wgd owns units
// [wgd*16, wgd*16+16) for BOTH directions, interleaved per loop iteration.
// Wave w owns k-slice [w*32, w*32+32); lane owns ONE row (gate=lane>>4, unit=lane&15)
// per direction -> wreg0[32] + wreg1[32].
__global__ __launch_bounds__(1024)
__attribute__((amdgpu_waves_per_eu(4, 4)))
void lstm_k(
    const float* __restrict__ whh_base,   // [2][2000][500]
    const float* __restrict__ gin,        // [2][4096][2048]
    const float* __restrict__ c0,         // [4][500]
    float* __restrict__ xout,             // [4096][1024]
    unsigned long long* __restrict__ hcomm, // [2][2][512]
    int layer) {
  __shared__ float part[2][16][68];       // [dir][wave][row]
  __shared__ float hbuf[16][32];

  const int tid = threadIdx.x;
  const int wgd = blockIdx.x;             // unit block [wgd*16, wgd*16+16)
  const int w = tid >> 6;
  const int lane = tid & 63;

  const int gate = lane >> 4;             // my row's gate (0=i,1=f,2=g,3=o)
  const int ul   = lane & 15;             // my row's local unit
  const int j    = wgd * 16 + ul;         // global unit (0..511)
  const int row  = gate * 500 + j;

  // ---- load recurrent weights for both directions (1 row x 32 k per lane each) ----
  float wreg0[32], wreg1[32];
#pragma unroll
  for (int i = 0; i < 32; i++) {
    int k = w * 32 + i;
    bool ok = (j < 500 && k < 500);
    wreg0[i] = ok ? whh_base[(size_t)row * 500 + k] : 0.0f;
    wreg1[i] = ok ? whh_base[(size_t)(2000 + row) * 500 + k] : 0.0f;
  }
#pragma unroll
  for (int i = 0; i < 32; i++) {
    asm volatile("" : "+v"(wreg0[i]));
    asm volatile("" : "+v"(wreg1[i]));
  }

  // wave0 lanes<16: persistent cell state per direction
  float cA = 0.0f, cB = 0.0f;
  if (w == 0 && lane < 16 && j < 500) {
    cA = c0[(layer * 2 + 0) * 500 + j];
    cB = c0[(layer * 2 + 1) * 500 + j];
  }

  unsigned long long* hc0 = hcomm;
  unsigned long long* hc1 = hcomm + 2 * HPAD;
  bool dead0 = false, dead1 = false;

  for (int t = 0; t < T_SEQ; t++) {
    const int p = t & 1;
    const int t0_in = t;
    const int t1_in = T_SEQ - 1 - t;

    const unsigned long long* hp0 = hc0 + (size_t)p * HPAD + w * 32 + (lane & 31);
    const unsigned long long* hp1 = hc1 + (size_t)p * HPAD + w * 32 + (lane & 31);

    // pre-issue dir1 poll (h1(t) is ~a full loop old -> usually already visible;
    // its latency is paid under the dir0 spin below)
    unsigned long long v1 = 0;
    if (!dead1) v1 = __hip_atomic_load(hp1, __ATOMIC_RELAXED, __HIP_MEMORY_SCOPE_AGENT);

    // wave0: prefetch input-projection gate values for both dirs (hidden under poll)
    float gi0 = 0.0f, gi1 = 0.0f;
    if (w == 0) {
      gi0 = gin[((size_t)0 * T_SEQ + t0_in) * 2048 + gate * 512 + j];
      gi1 = gin[((size_t)1 * T_SEQ + t1_in) * 2048 + gate * 512 + j];
    }

    // ================= dir0 sub-step =================
    unsigned long long v0 = 0;
    if (!dead0) {
      int guard = 0;
      for (;;) {
        v0 = __hip_atomic_load(hp0, __ATOMIC_RELAXED, __HIP_MEMORY_SCOPE_AGENT);
        if (__all((int)((unsigned)v0 == (unsigned)t))) break;
        if (++guard > (1 << 22)) { dead0 = true; break; }
      }
    }
    {
      float hval = __uint_as_float((unsigned)(v0 >> 32));
      if (lane < 32) hbuf[w][lane] = hval;     // same-wave RAW, lgkmcnt-ordered
      float a = 0.0f;
#pragma unroll
      for (int b = 0; b < 8; b++) {
        float4 hv = *reinterpret_cast<const float4*>(&hbuf[w][b * 4]);
        a = fmaf(wreg0[b * 4 + 0], hv.x, a);
        a = fmaf(wreg0[b * 4 + 1], hv.y, a);
        a = fmaf(wreg0[b * 4 + 2], hv.z, a);
        a = fmaf(wreg0[b * 4 + 3], hv.w, a);
      }
      part[0][w][lane] = a;
    }
    __syncthreads();                           // bar1
    if (w == 0) {
      float s = gi0;
#pragma unroll
      for (int q = 0; q < 16; q++) s += part[0][q][lane];
      float nl = (gate == 2) ? ftanhf(s) : fsig(s);
      float xf = __shfl(nl, lane + 16, 64);
      float xg = __shfl(nl, lane + 32, 64);
      float xo = __shfl(nl, lane + 48, 64);
      if (lane < 16) {
        cA = xf * cA + nl * xg;                // nl = input gate here
        float h = xo * ftanhf(cA);
        __hip_atomic_store(hc0 + (size_t)((t + 1) & 1) * HPAD + j,
                           pack_hv((unsigned)(t + 1), h),
                           __ATOMIC_RELAXED, __HIP_MEMORY_SCOPE_AGENT);
        if (j < 500) xout[(size_t)t0_in * 1024 + j] = h;
      }
    }

    // ================= dir1 sub-step =================
    if (!dead1 && !__all((int)((unsigned)v1 == (unsigned)t))) {
      int guard = 0;
      for (;;) {
        v1 = __hip_atomic_load(hp1, __ATOMIC_RELAXED, __HIP_MEMORY_SCOPE_AGENT);
        if (__all((int)((unsigned)v1 == (unsigned)t))) break;
        if (++guard > (1 << 22)) { dead1 = true; break; }
      }
    }
    {
      float hval = __uint_as_float((unsigned)(v1 >> 32));
      if (lane < 32) hbuf[w][lane] = hval;     // wave-serial reuse: dir0 reads done
      float a = 0.0f;
#pragma unroll
      for (int b = 0; b < 8; b++) {
        float4 hv = *reinterpret_cast<const float4*>(&hbuf[w][b * 4]);
        a = fmaf(wreg1[b * 4 + 0], hv.x, a);
        a = fmaf(wreg1[b * 4 + 1], hv.y, a);
        a = fmaf(wreg1[b * 4 + 2], hv.z, a);
        a = fmaf(wreg1[b * 4 + 3], hv.w, a);
      }
      part[1][w][lane] = a;
    }
    __syncthreads();                           // bar2
    if (w == 0) {
      float s = gi1;
#pragma unroll
      for (int q = 0; q < 16; q++) s += part[1][q][lane];
      float nl = (gate == 2) ? ftanhf(s) : fsig(s);
      float xf = __shfl(nl, lane + 16, 64);
      float xg = __shfl(nl, lane + 32, 64);
      float xo = __shfl(nl, lane + 48, 64);
      if (lane < 16) {
        cB = xf * cB + nl * xg;
        float h = xo * ftanhf(cB);
        __hip_atomic_store(hc1 + (size_t)((t + 1) & 1) * HPAD + j,
                           pack_hv((unsigned)(t + 1), h),
                           __ATOMIC_RELAXED, __HIP_MEMORY_SCOPE_AGENT);
        if (j < 500) xout[(size_t)t1_in * 1024 + HPAD + j] = h;
      }
    }
  }
}

// feats[t][tag] = sum_k x2[t][k]*w_out[tag][k_real] + b_out[tag]
__global__ __launch_bounds__(256) void feats_k(
    const float* __restrict__ x2, const float* __restrict__ w_out,
    const float* __restrict__ b_out, float* __restrict__ feats) {
  int tid = threadIdx.x;
  int tag = tid & 15, tl = tid >> 4;
  int t = blockIdx.x * 16 + tl;
  float acc = 0.0f;
  for (int k = 0; k < 1024; k++) {
    int jk = k & 511;
    if (jk < 500)
      acc = fmaf(x2[(size_t)t * 1024 + k], w_out[tag * 1000 + (k >> 9) * 500 + jk], acc);
  }
  feats[t * 16 + tag] = acc + b_out[tag];
}

__global__ __launch_bounds__(256) void viterbi_k(
    const float* __restrict__ feats, const float* __restrict__ trans,
    int* __restrict__ bptr, float* __restrict__ out) {
  __shared__ float sfin[NTAG];
  __shared__ int sbest;
  int tid = threadIdx.x;
  if (tid < 64) {
    int tag = tid & 15;
    float treg[16];
#pragma unroll
    for (int p = 0; p < 16; p++) treg[p] = trans[tag * 16 + p];
    float s = (tag == 14) ? 0.0f : -10000.0f;   // START=14
    for (int t = 0; t < T_SEQ; t++) {
      float best = -3.4e38f;
      int barg = 0;
#pragma unroll
      for (int p = 0; p < 16; p++) {
        float cand = __shfl(s, p, 16) + treg[p];
        if (cand > best) { best = cand; barg = p; }   // strict > : first-max (np.argmax)
      }
      s = best + feats[t * 16 + tag];
      if (tid < 16) bptr[t * 16 + tag] = barg;
    }
    s += trans[15 * 16 + tag];                   // STOP=15
    if (tid < 16) sfin[tag] = s;
  }
  __syncthreads();
  if (tid == 0) {
    float best = -3.4e38f;
    int bt = 0;
    for (int p = 0; p < 16; p++) {
      float vv = sfin[p];
      if (vv > best) { best = vv; bt = p; }
    }
    out[0] = best;
    sbest = bt;
  }
  __syncthreads();
  int bt = sbest;
  for (int i = tid; i < T_SEQ - 1; i += blockDim.x)
    out[1 + i] = (float)bptr[(i + 1) * 16 + bt];
  if (tid == 0) out[T_SEQ] = (float)bt;
}

extern "C" void kernel_launch(void* const* d_in, const int* in_sizes, int n_in,
                              void* d_out, int out_size, void* d_ws, size_t ws_size,
                              hipStream_t stream) {
  const int*   sent  = (const int*)d_in[0];
  const float* embed = (const float*)d_in[1];
  const float* wih0  = (const float*)d_in[2];
  const float* whh0  = (const float*)d_in[3];
  const float* bih0  = (const float*)d_in[4];
  const float* bhh0  = (const float*)d_in[5];
  const float* wih1  = (const float*)d_in[6];
  const float* whh1  = (const float*)d_in[7];
  const float* bih1  = (const float*)d_in[8];
  const float* bhh1  = (const float*)d_in[9];
  const float* w_out = (const float*)d_in[10];
  const float* b_out = (const float*)d_in[11];
  const float* trans = (const float*)d_in[12];
  const float* h0    = (const float*)d_in[13];
  const float* c0    = (const float*)d_in[14];
  float* out = (float*)d_out;

  char* ws = (char*)d_ws;
  float* x0    = (float*)(ws + 0);
  float* x1    = (float*)(ws + 8388608);
  float* x2    = (float*)(ws + 25165824);
  float* gin   = (float*)(ws + 41943040);
  float* feats = (float*)(ws + 109051904);
  int*   bptr  = (int*)(ws + 109314048);
  unsigned long long* hcomm = (unsigned long long*)(ws + 109576192);
  // Scratch reuse (non-overlapping lifetimes):
  float* Wp = x2;                         // dense packed W; dead before lstm L1 writes x2
  float* bp = (float*)(ws + 109314048);   // packed bias in bptr slot; dead before viterbi

  // zero x1 so its pad columns are 0 for the dense L1 gemm A-reads
  zero_k<<<1024, 256, 0, stream>>>(x1, T_SEQ * 1024);
  embed_k<<<T_SEQ, 256, 0, stream>>>(sent, embed, x0);

  // layer 0
  wpack_k<<<dim3(2048, 2), 256, 0, stream>>>(wih0, bih0, bhh0, 500, 512, Wp, bp);
  gin_gemm_k<<<dim3(16, 32, 2), 256, 0, stream>>>(x0, 512, Wp, bp, gin);
  hinit_k<<<2, 1024, 0, stream>>>(h0, 0, hcomm);
  lstm_k<<<32, 1024, 0, stream>>>(whh0, gin, c0, x1, hcomm, 0);

  // layer 1
  wpack_k<<<dim3(2048, 2), 256, 0, stream>>>(wih1, bih1, bhh1, 1000, 1024, Wp, bp);
  gin_gemm_k<<<dim3(16, 32, 2), 256, 0, stream>>>(x1, 1024, Wp, bp, gin);
  hinit_k<<<2, 1024, 0, stream>>>(h0, 1, hcomm);
  lstm_k<<<32, 1024, 0, stream>>>(whh1, gin, c0, x2, hcomm, 1);

  // output projection + viterbi
  feats_k<<<T_SEQ / 16, 256, 0, stream>>>(x2, w_out, b_out, feats);
  viterbi_k<<<1, 256, 0, stream>>>(feats, trans, bptr, out);
}

// Round 10
// 13757.607 us; speedup vs baseline: 1.3803x; 1.3803x over previous
//
#include <hip/hip_runtime.h>

// LSTM-CRF on MI355X.
// Pipeline: embed -> gemm(gin L0) -> lstm L0 -> gemm(gin L1) -> lstm L1 -> feats -> viterbi.
// Recurrence: 32 WGs per direction (16 units each, round-7 parallel structure: both dirs
// concurrent on different CUs). h exchanged per step via tagged u64 {tag:u32, h:f32}
// device-scope relaxed mailbox (proven). Round-9 lesson: interleaving both dirs in one WG
// gives 2,200cy/step-equivalent but serializes the dirs -> wall-clock loss; keep parallel.
// Round-10: trim wave0's serial finish (~900cy of the 3,600cy step): hardware-exp gates
// (v_exp_f32+v_rcp_f32 instead of branchy libm tanhf/expf), s_setprio(1) around the finish
// (wave0 wins VALU arbitration vs 15 spinning waves), publish h before the xout store.
// Score threshold is 227.84 and path elements are <=15, so ~1e-6 gate error is free.

#define T_SEQ 4096
#define HPAD  512
#define NTAG  16

// ---------------- workspace layout (bytes) ----------------
// x0   : [4096][512]  f32   8388608  @ 0
// x1   : [4096][1024] f32  16777216  @ 8388608
// x2   : [4096][1024] f32  16777216  @ 25165824
// gin  : [2][4096][2048] f32 67108864 @ 41943040
// feats: [4096][16] f32     262144  @ 109051904
// bptr : [4096][16] i32     262144  @ 109314048
// hcomm: [2][2][512] u64     16384  @ 109576192

__global__ void zero_k(float* __restrict__ p, int n) {
  int i = blockIdx.x * blockDim.x + threadIdx.x;
  int stride = gridDim.x * blockDim.x;
  for (; i < n; i += stride) p[i] = 0.0f;
}

__global__ void embed_k(const int* __restrict__ sent, const float* __restrict__ ew,
                        float* __restrict__ x0) {
  int t = blockIdx.x;
  int row = sent[t];
  for (int k = threadIdx.x; k < HPAD; k += blockDim.x)
    x0[(size_t)t * HPAD + k] = (k < 500) ? ew[(size_t)row * 500 + k] : 0.0f;
}

// G[dir][t][n] = sum_k A[t][k] * Wmap[dir][n][k] + bias[n]  (f32, 128x128 tile, 8x8/thread)
__global__ __launch_bounds__(256) void gin_gemm_k(
    const float* __restrict__ A, int KA,
    const float* __restrict__ wih, const float* __restrict__ bih,
    const float* __restrict__ bhh, int Kreal, float* __restrict__ G) {
  const int dir = blockIdx.z;
  const int bm = blockIdx.y, bn = blockIdx.x;
  const float* W = wih + (size_t)dir * 2000 * Kreal;

  __shared__ float As[16][128];
  __shared__ float Bs[16][128];

  const int tid = threadIdx.x;
  const int tx = tid & 15, ty = tid >> 4;
  float acc[8][8] = {};

  for (int k0 = 0; k0 < KA; k0 += 16) {
#pragma unroll
    for (int q = 0; q < 2; q++) {
      int f4 = tid + q * 256;              // 0..511
      int m = f4 >> 2, kc = (f4 & 3) * 4;
      float4 av = *reinterpret_cast<const float4*>(A + (size_t)(bm * 128 + m) * KA + k0 + kc);
      As[kc + 0][m] = av.x; As[kc + 1][m] = av.y;
      As[kc + 2][m] = av.z; As[kc + 3][m] = av.w;
    }
#pragma unroll
    for (int q = 0; q < 2; q++) {
      int f4 = tid + q * 256;
      int n = f4 >> 2, kc = (f4 & 3) * 4;
      int nn = bn * 128 + n;
      int gate = nn >> 9, j = nn & 511;
#pragma unroll
      for (int e = 0; e < 4; e++) {
        int k = k0 + kc + e;
        int jk = k & 511, half = k >> 9;
        float v = 0.0f;
        if (j < 500 && jk < 500)
          v = W[(size_t)(gate * 500 + j) * Kreal + half * 500 + jk];
        Bs[kc + e][n] = v;
      }
    }
    __syncthreads();
#pragma unroll
    for (int kk = 0; kk < 16; kk++) {
      float a[8], b[8];
      *reinterpret_cast<float4*>(&a[0]) = *reinterpret_cast<const float4*>(&As[kk][ty * 8]);
      *reinterpret_cast<float4*>(&a[4]) = *reinterpret_cast<const float4*>(&As[kk][ty * 8 + 4]);
      *reinterpret_cast<float4*>(&b[0]) = *reinterpret_cast<const float4*>(&Bs[kk][tx * 8]);
      *reinterpret_cast<float4*>(&b[4]) = *reinterpret_cast<const float4*>(&Bs[kk][tx * 8 + 4]);
#pragma unroll
      for (int i = 0; i < 8; i++)
#pragma unroll
        for (int j = 0; j < 8; j++) acc[i][j] = fmaf(a[i], b[j], acc[i][j]);
    }
    __syncthreads();
  }
#pragma unroll
  for (int i = 0; i < 8; i++) {
#pragma unroll
    for (int j = 0; j < 8; j++) {
      int m = bm * 128 + ty * 8 + i;
      int nn = bn * 128 + tx * 8 + j;
      int gate = nn >> 9, ju = nn & 511;
      float o = 0.0f;
      if (ju < 500) {
        int r = gate * 500 + ju;
        o = acc[i][j] + bih[dir * 2000 + r] + bhh[dir * 2000 + r];
      }
      G[((size_t)dir * T_SEQ + m) * 2048 + nn] = o;
    }
  }
}

__device__ __forceinline__ unsigned long long pack_hv(unsigned tag, float h) {
  return (unsigned long long)tag | ((unsigned long long)__float_as_uint(h) << 32);
}

// fast sigmoid/tanh: v_exp_f32 + v_rcp_f32, branch-free, saturates correctly.
__device__ __forceinline__ float fsig(float x) {
  float e = __expf(-x);
  return __builtin_amdgcn_rcpf(1.0f + e);
}
__device__ __forceinline__ float ftanhf(float x) {
  return fmaf(2.0f, fsig(x + x), -1.0f);
}

__global__ void hinit_k(const float* __restrict__ h0, int layer,
                        unsigned long long* __restrict__ hcomm) {
  int i = blockIdx.x * blockDim.x + threadIdx.x;   // 0..2047
  int dir = i >> 10, par = (i >> 9) & 1, j = i & 511;
  unsigned long long v;
  if (par == 0) {
    float h = (j < 500) ? h0[(layer * 2 + dir) * 500 + j] : 0.0f;
    v = pack_hv(0u, h);
  } else {
    v = 0xFFFFFFFFull;   // sentinel tag, value 0
  }
  hcomm[(size_t)(dir * 2 + par) * HPAD + j] = v;
}

// Persistent recurrence kernel: 64 WGs x 1024 threads; WG = (dir = blockIdx>>5,
// wgd = blockIdx&31) owns units [wgd*16, wgd*16+16)  (64 rows = 4 gates x 16 units).
// Wave w owns k-slice [w*32, w*32+32); lane owns ONE row (gate=lane>>4, unit=lane&15).
// One barrier per step; wave0 sums 16 partials per row, fast gates, publishes.
__global__ __launch_bounds__(1024)
__attribute__((amdgpu_waves_per_eu(4, 4)))
void lstm_k(
    const float* __restrict__ whh_base,   // [2][2000][500]
    const float* __restrict__ gin,        // [2][4096][2048]
    const float* __restrict__ c0,         // [4][500]
    float* __restrict__ xout,             // [4096][1024]
    unsigned long long* __restrict__ hcomm, // [2][2][512]
    int layer) {
  __shared__ float part[16][68];          // pad 68: conflict-free on both patterns
  __shared__ float hbuf[16][32];

  const int tid = threadIdx.x;
  const int dir = blockIdx.x >> 5;
  const int wgd = blockIdx.x & 31;        // unit block [wgd*16, wgd*16+16)
  const int w = tid >> 6;
  const int lane = tid & 63;

  const int gate = lane >> 4;             // my row's gate (0=i,1=f,2=g,3=o)
  const int ul   = lane & 15;             // my row's local unit
  const int j    = wgd * 16 + ul;         // global unit (0..511)
  const int row  = gate * 500 + j;

  // ---- load recurrent weights into registers (1 row x 32 k per lane) ----
  float wreg[32];
  const float* Wd = whh_base + (size_t)dir * 2000 * 500;
#pragma unroll
  for (int i = 0; i < 32; i++) {
    int k = w * 32 + i;
    wreg[i] = (j < 500 && k < 500) ? Wd[(size_t)row * 500 + k] : 0.0f;
  }
#pragma unroll
  for (int i = 0; i < 32; i++) asm volatile("" : "+v"(wreg[i]));

  // wave0 lanes<16: persistent cell state (one unit per lane)
  float c = 0.0f;
  if (w == 0 && lane < 16 && j < 500) c = c0[(layer * 2 + dir) * 500 + j];

  unsigned long long* hcd = hcomm + (size_t)dir * 2 * HPAD;
  bool dead = false;

  for (int t = 0; t < T_SEQ; t++) {
    const int t_in = (dir == 0) ? t : (T_SEQ - 1 - t);

    // prefetch input-projection gate value for my row (latency hidden under poll)
    float gi = 0.0f;
    if (w == 0) {
      const float* gb = gin + ((size_t)dir * T_SEQ + t_in) * 2048;
      gi = gb[gate * 512 + j];
    }

    // ---- poll my wave's h k-slice (tag==t), device-scope (proven) ----
    unsigned long long v = 0;
    if (!dead) {
      const unsigned long long* hp =
          hcd + (size_t)(t & 1) * HPAD + w * 32 + (lane & 31);
      int guard = 0;
      for (;;) {
        v = __hip_atomic_load(hp, __ATOMIC_RELAXED, __HIP_MEMORY_SCOPE_AGENT);
        if (__all((int)((unsigned)v == (unsigned)t))) break;
        if (++guard > (1 << 22)) { dead = true; break; }   // bail, never hang
      }
    }
    float hval = __uint_as_float((unsigned)(v >> 32));

    // ---- broadcast h within the wave via LDS, matvec partial for my row ----
    if (lane < 32) hbuf[w][lane] = hval;   // same-wave RAW, ordered by lgkmcnt
    float a = 0.0f;
#pragma unroll
    for (int b = 0; b < 8; b++) {
      float4 hv = *reinterpret_cast<const float4*>(&hbuf[w][b * 4]);
      a = fmaf(wreg[b * 4 + 0], hv.x, a);
      a = fmaf(wreg[b * 4 + 1], hv.y, a);
      a = fmaf(wreg[b * 4 + 2], hv.z, a);
      a = fmaf(wreg[b * 4 + 3], hv.w, a);
    }
    part[w][lane] = a;
    __syncthreads();   // the ONLY barrier per step

    // ---- wave0: per-row linear sum of 16 partials, fast gates, publish ----
    // Race-free vs next step: waves can only overwrite part(t+1) after polling
    // h(t+1), which requires the publish below -- which follows these reads.
    if (w == 0) {
      __builtin_amdgcn_s_setprio(1);       // win issue arbitration vs spinning waves
      float s = gi;
#pragma unroll
      for (int q = 0; q < 16; q++) s += part[q][lane];
      float nl = (gate == 2) ? ftanhf(s) : fsig(s);
      float xf = __shfl(nl, lane + 16, 64);
      float xg = __shfl(nl, lane + 32, 64);
      float xo = __shfl(nl, lane + 48, 64);
      if (lane < 16) {
        c = xf * c + nl * xg;              // nl here is xi (gate 0)
        float h = xo * ftanhf(c);
        // publish FIRST (starts the LLC trip), then the xout store
        __hip_atomic_store(hcd + (size_t)((t + 1) & 1) * HPAD + j,
                           pack_hv((unsigned)(t + 1), h),
                           __ATOMIC_RELAXED, __HIP_MEMORY_SCOPE_AGENT);
        if (j < 500)
          xout[(size_t)t_in * 1024 + (size_t)dir * HPAD + j] = h;
      }
      __builtin_amdgcn_s_setprio(0);
    }
  }
}

// feats[t][tag] = sum_k x2[t][k]*w_out[tag][k_real] + b_out[tag]
__global__ __launch_bounds__(256) void feats_k(
    const float* __restrict__ x2, const float* __restrict__ w_out,
    const float* __restrict__ b_out, float* __restrict__ feats) {
  int tid = threadIdx.x;
  int tag = tid & 15, tl = tid >> 4;
  int t = blockIdx.x * 16 + tl;
  float acc = 0.0f;
  for (int k = 0; k < 1024; k++) {
    int jk = k & 511;
    if (jk < 500)
      acc = fmaf(x2[(size_t)t * 1024 + k], w_out[tag * 1000 + (k >> 9) * 500 + jk], acc);
  }
  feats[t * 16 + tag] = acc + b_out[tag];
}

__global__ __launch_bounds__(256) void viterbi_k(
    const float* __restrict__ feats, const float* __restrict__ trans,
    int* __restrict__ bptr, float* __restrict__ out) {
  __shared__ float sfin[NTAG];
  __shared__ int sbest;
  int tid = threadIdx.x;
  if (tid < 64) {
    int tag = tid & 15;
    float treg[16];
#pragma unroll
    for (int p = 0; p < 16; p++) treg[p] = trans[tag * 16 + p];
    float s = (tag == 14) ? 0.0f : -10000.0f;   // START=14
    for (int t = 0; t < T_SEQ; t++) {
      float best = -3.4e38f;
      int barg = 0;
#pragma unroll
      for (int p = 0; p < 16; p++) {
        float cand = __shfl(s, p, 16) + treg[p];
        if (cand > best) { best = cand; barg = p; }   // strict > : first-max (np.argmax)
      }
      s = best + feats[t * 16 + tag];
      if (tid < 16) bptr[t * 16 + tag] = barg;
    }
    s += trans[15 * 16 + tag];                   // STOP=15
    if (tid < 16) sfin[tag] = s;
  }
  __syncthreads();
  if (tid == 0) {
    float best = -3.4e38f;
    int bt = 0;
    for (int p = 0; p < 16; p++) {
      float vv = sfin[p];
      if (vv > best) { best = vv; bt = p; }
    }
    out[0] = best;
    sbest = bt;
  }
  __syncthreads();
  int bt = sbest;
  for (int i = tid; i < T_SEQ - 1; i += blockDim.x)
    out[1 + i] = (float)bptr[(i + 1) * 16 + bt];
  if (tid == 0) out[T_SEQ] = (float)bt;
}

extern "C" void kernel_launch(void* const* d_in, const int* in_sizes, int n_in,
                              void* d_out, int out_size, void* d_ws, size_t ws_size,
                              hipStream_t stream) {
  const int*   sent  = (const int*)d_in[0];
  const float* embed = (const float*)d_in[1];
  const float* wih0  = (const float*)d_in[2];
  const float* whh0  = (const float*)d_in[3];
  const float* bih0  = (const float*)d_in[4];
  const float* bhh0  = (const float*)d_in[5];
  const float* wih1  = (const float*)d_in[6];
  const float* whh1  = (const float*)d_in[7];
  const float* bih1  = (const float*)d_in[8];
  const float* bhh1  = (const float*)d_in[9];
  const float* w_out = (const float*)d_in[10];
  const float* b_out = (const float*)d_in[11];
  const float* trans = (const float*)d_in[12];
  const float* h0    = (const float*)d_in[13];
  const float* c0    = (const float*)d_in[14];
  float* out = (float*)d_out;

  char* ws = (char*)d_ws;
  float* x0    = (float*)(ws + 0);
  float* x1    = (float*)(ws + 8388608);
  float* x2    = (float*)(ws + 25165824);
  float* gin   = (float*)(ws + 41943040);
  float* feats = (float*)(ws + 109051904);
  int*   bptr  = (int*)(ws + 109314048);
  unsigned long long* hcomm = (unsigned long long*)(ws + 109576192);

  // zero x1+x2 (contiguous 32MB) so pad columns are 0
  zero_k<<<2048, 256, 0, stream>>>(x1, 2 * T_SEQ * 1024);
  embed_k<<<T_SEQ, 256, 0, stream>>>(sent, embed, x0);

  // layer 0
  gin_gemm_k<<<dim3(16, 32, 2), 256, 0, stream>>>(x0, 512, wih0, bih0, bhh0, 500, gin);
  hinit_k<<<2, 1024, 0, stream>>>(h0, 0, hcomm);
  lstm_k<<<64, 1024, 0, stream>>>(whh0, gin, c0, x1, hcomm, 0);

  // layer 1
  gin_gemm_k<<<dim3(16, 32, 2), 256, 0, stream>>>(x1, 1024, wih1, bih1, bhh1, 1000, gin);
  hinit_k<<<2, 1024, 0, stream>>>(h0, 1, hcomm);
  lstm_k<<<64, 1024, 0, stream>>>(whh1, gin, c0, x2, hcomm, 1);

  // output projection + viterbi
  feats_k<<<T_SEQ / 16, 256, 0, stream>>>(x2, w_out, b_out, feats);
  viterbi_k<<<1, 256, 0, stream>>>(feats, trans, bptr, out);
}